// Round 4
// baseline (249.180 us; speedup 1.0000x reference)
//
#include <hip/hip_runtime.h>

// Collapsed problem (channel-sum commutes with the linear conv):
//   out[n,d,h,w] = sum_{i,kd,kh,kw} x[n,i,d+kd,h+kh,w+kw] * Wsum[i,kd,kh,kw] + C
//   Wsum = 0.5 * sum_o conv_weight[o,...]   (32*27 = 864 floats)
//   C    = sum_o (0.5*conv_bias[o] + bias[o])
// x: (8,32,32,64,64) fp32; out: (8,30,62,62) fp32.
//
// Structure: 128-thread blocks, grid 512 = 2 blocks/CU. Each thread owns
// 2(d) x 1(h) x 8(w) outputs -> register d-blocking: 12 row-reads feed 432
// FMAs (0.28 LDS-floats/FMA, 0.67x vs 1-d blocking).
//
// LDS tile[slice][row][16 chunks of 16B]; chunk c stored at position
// pi(c): c=2t -> (3t)&15 ; c=2t+1 -> (3t+8)&15  (bijection). Read positions
// are thread-constant P0=(3s)&15, P1=(3s+8)&15, P2=(3s+3)&15, and
// {P mod 8 : s=0..7} is a lane-permutation -> every row-octet tiles all 32
// banks -> conflict-free ds_read_b128/b64. Staging applies pi^{-1} to the
// GLOBAL source address (linear LDS dest, global_load_lds rule).

#define XD 32
#define XH 64
#define XW 64
#define DOUT 30
#define HOUT 62
#define WOUT 62
#define DT 4            // output d per block (2 slots x 2)
#define HT 8
#define TILE_SLICES 6   // DT+2
#define TILE_ROWS 10    // HT+2
#define TILE_FLOATS (TILE_SLICES * TILE_ROWS * 64)  // 3840 floats = 15 KiB
#define CHUNKS (TILE_FLOATS / 4)                    // 960 x 16B chunks
#define ROUNDS 8                                    // ceil(960/128)
#define CH_STRIDE (XD * XH * XW)

__global__ __launch_bounds__(128, 2)
void conv3d_chansum_kernel(const float* __restrict__ x,
                           const float* __restrict__ cw,
                           const float* __restrict__ cb,
                           const float* __restrict__ pb,
                           float* __restrict__ out) {
  __shared__ float tile[2][TILE_FLOATS];  // 30 KiB double buffer
  __shared__ float wl[897];               // [32][28] padded Wsum + wl[896]=C

  const int tid = threadIdx.x;
  const int hb = blockIdx.x;  // 0..7
  const int db = blockIdx.y;  // 0..7
  const int n  = blockIdx.z;  // 0..7
  const int h0 = hb * HT;
  const int d0 = db * DT;

  // thread -> (dts, ht, s): s=w-strip, ht=row, dts=d-pair slot
  const int s    = tid & 7;
  const int slot = tid >> 3;   // 0..15
  const int ht   = slot & 7;
  const int dts  = slot >> 3;  // 0..1 (wave-uniform)

  const float* xn = x + (size_t)n * (32u * CH_STRIDE);

  // ---- hoisted staging addresses (channel-invariant) ----
  // chunk k: slice sd=k/160, row r=(k%160)>>4, position p=k&15.
  // source chunk = pi^{-1}(p): t1=(11p)&15; t1<8 -> 2*t1 else 2*((11*(p-8))&15)+1
  int  soff[ROUNDS];
  bool svalid[ROUNDS];
#pragma unroll
  for (int round = 0; round < ROUNDS; ++round) {
    int k   = tid + round * 128;
    int sd  = k / 160;
    int rem = k - sd * 160;
    int r   = rem >> 4;
    int p   = rem & 15;
    int t1  = (11 * p) & 15;
    int csrc = (t1 < 8) ? (2 * t1) : (2 * ((11 * (p - 8)) & 15) + 1);
    int dd = d0 + sd, hh = h0 + r;
    svalid[round] = (k < CHUNKS) & (dd < XD) & (hh < XH);
    soff[round]   = dd * (XH * XW) + hh * XW + csrc * 4;
  }
  const int ldsoff = (tid & ~63) * 4;  // wave-uniform float offset (+ round*512)

  auto stage = [&](float* buf, int ch) {
    const float* xnc = xn + (size_t)ch * CH_STRIDE;
#pragma unroll
    for (int round = 0; round < ROUNDS; ++round) {
      if (svalid[round]) {
        __builtin_amdgcn_global_load_lds(
            (const __attribute__((address_space(1))) void*)(xnc + soff[round]),
            (__attribute__((address_space(3))) void*)(buf + round * 512 + ldsoff),
            16, 0, 0);
      }
    }
  };

  // thread-constant read positions (conflict-free by construction)
  const int P0 = (3 * s) & 15;
  const int P1 = (3 * s + 8) & 15;
  const int P2 = (3 * s + 3) & 15;

  float acc[2][8];
#pragma unroll
  for (int dl = 0; dl < 2; ++dl)
#pragma unroll
    for (int j = 0; j < 8; ++j) acc[dl][j] = 0.f;

  // prologue: issue channel-0 staging; weight pre-sum overlaps the load latency
  stage(tile[0], 0);
  for (int e = tid; e < 864; e += 128) {
    int i = e / 27;
    int j = e - i * 27;
    float ssum = 0.f;
#pragma unroll 8
    for (int o = 0; o < 64; ++o) ssum += cw[o * 864 + e];
    wl[i * 28 + j] = 0.5f * ssum;
  }
  if (tid == 0) {
    float ssum = 0.f;
    for (int o = 0; o < 64; ++o) ssum += 0.5f * cb[o] + pb[o];
    wl[896] = ssum;
  }
  __syncthreads();  // tile[0] staged (vmcnt0 drain), wl visible

#pragma unroll 1
  for (int ch = 0; ch < 32; ++ch) {
    const float* buf = tile[ch & 1];
    // issue next channel's loads first -> latency hides under this channel's FMAs
    if (ch < 31) stage(tile[(ch & 1) ^ 1], ch + 1);

    float wr[28];
#pragma unroll
    for (int q = 0; q < 7; ++q)
      *(float4*)&wr[4 * q] = *(const float4*)&wl[ch * 28 + 4 * q];

    // 4 slices x 3 kh row-reads; each row feeds 1-2 of the thread's 2 d-outputs
#pragma unroll
    for (int i = 0; i < 4; ++i) {
      const int slice = 2 * dts + i;  // 0..5
#pragma unroll
      for (int kh = 0; kh < 3; ++kh) {
        const int base = (slice * TILE_ROWS + (ht + kh)) * 64;
        float4 a  = *(const float4*)&buf[base + (P0 << 2)];
        float4 b  = *(const float4*)&buf[base + (P1 << 2)];
        float2 c2 = *(const float2*)&buf[base + (P2 << 2)];
        float xv[10] = {a.x, a.y, a.z, a.w, b.x, b.y, b.z, b.w, c2.x, c2.y};
#pragma unroll
        for (int kd = 0; kd < 3; ++kd) {
          const int dl = i - kd;  // compile-time; output d = d0 + 2*dts + dl
          if (dl >= 0 && dl < 2) {
            const int wb = kd * 9 + kh * 3;
#pragma unroll
            for (int j = 0; j < 8; ++j)
              acc[dl][j] = fmaf(xv[j], wr[wb],
                           fmaf(xv[j + 1], wr[wb + 1],
                           fmaf(xv[j + 2], wr[wb + 2], acc[dl][j])));
          }
        }
      }
    }

    __syncthreads();  // WAR for next stage + (vmcnt0 drain) RAW for ch+1 tile
  }

  // epilogue: out[n][d0+2*dts+dl][h0+ht][8s..8s+7], masked at ragged edges
  const float Cc  = wl[896];
  const int   how = h0 + ht;
  const int   nw  = min(8, WOUT - s * 8);
#pragma unroll
  for (int dl = 0; dl < 2; ++dl) {
    const int dow = d0 + 2 * dts + dl;
    if (dow < DOUT && how < HOUT) {
      float* op = out + (((size_t)n * DOUT + dow) * HOUT + how) * WOUT + s * 8;
#pragma unroll
      for (int j = 0; j < 4; ++j) {
        if (2 * j < nw) {
          float2 v;
          v.x = acc[dl][2 * j] + Cc;
          v.y = acc[dl][2 * j + 1] + Cc;
          *(float2*)&op[2 * j] = v;
        }
      }
    }
  }
}

extern "C" void kernel_launch(void* const* d_in, const int* in_sizes, int n_in,
                              void* d_out, int out_size, void* d_ws, size_t ws_size,
                              hipStream_t stream) {
  const float* x  = (const float*)d_in[0];  // (8,32,32,64,64)
  const float* cw = (const float*)d_in[1];  // (64,32,3,3,3)
  const float* cb = (const float*)d_in[2];  // (64,)
  const float* pb = (const float*)d_in[3];  // (64,1,1,1)
  float* out = (float*)d_out;               // (8,30,62,62)

  dim3 grid(8, 8, 8);  // (hb, db, n) -> 512 blocks = 2 per CU
  conv3d_chansum_kernel<<<grid, 128, 0, stream>>>(x, cw, cb, pb, out);
}

// Round 7
// 224.611 us; speedup vs baseline: 1.1094x; 1.1094x over previous
//
#include <hip/hip_runtime.h>

// Collapsed problem (channel-sum commutes with the linear conv):
//   out[n,d,h,w] = sum_{i,kd,kh,kw} x[n,i,d+kd,h+kh,w+kw] * Wsum[i,kd,kh,kw] + C
//   Wsum = 0.5 * sum_o conv_weight[o,...]   (32*27 = 864 floats)
//   C    = sum_o (0.5*conv_bias[o] + bias[o])
// x: (8,32,32,64,64) fp32; out: (8,30,62,62) fp32.
//
// Barrier-free per-wave pipeline (R5 structure) + DPP neighbor-fetch:
//  - 256-thr blocks, grid 512 (2 blocks/CU -> 8 waves/CU, 2/SIMD).
//  - Wave owns output slab d=d0+wid, h=h0..h0+7, w=0..63 (8 w-floats/thread).
//  - Wave-PRIVATE double-buffered LDS tile [3][10][64] (pad to 2048 floats);
//    no cross-wave sharing -> zero __syncthreads in the channel loop.
//  - Per channel: exactly 8 always-issued clamped global_load_lds (1 KiB);
//    counted `s_waitcnt vmcnt(8)` (T4) == previous channel landed; trailing
//    `lgkmcnt(0)` guards WAR on the buffer re-staged next iteration.
//  - Chunk permutation pi(c): 2t->(3t)&15, 2t+1->(3t+8)&15; read positions
//    thread-constant (P0,P1); pi^{-1} pre-applied to the GLOBAL source
//    address, LDS dest linear (global_load_lds rule).
//  - xv[8],xv[9] come from lane+1 via v_mov_b32_dpp row_shl:1 (no b64 read);
//    boundary/s=7 lanes get garbage -> only feeds epilogue-masked outputs.

#define XD 32
#define XH 64
#define XW 64
#define DOUT 30
#define HOUT 62
#define WOUT 62
#define CH_STRIDE (XD * XH * XW)
#define WBUF_FLOATS 2048  // 3*10*64 = 1920 used + pad (chunks 480..511)

__device__ __forceinline__ float nextlane(float v) {
  // row_shl:1 -> dest lane i gets src lane i+1 (within 16-lane row);
  // bound_ctrl=true: out-of-row lanes read 0 (those lanes are masked anyway).
  return __int_as_float(
      __builtin_amdgcn_mov_dpp(__float_as_int(v), 0x101, 0xF, 0xF, true));
}

__global__ __launch_bounds__(256, 2)
void conv3d_chansum_kernel(const float* __restrict__ x,
                           const float* __restrict__ cw,
                           const float* __restrict__ cb,
                           const float* __restrict__ pb,
                           float* __restrict__ out) {
  __shared__ float wavebuf[4][2][WBUF_FLOATS];  // 64 KiB, wave-private halves
  __shared__ float wl[897];                     // [32][28] Wsum + wl[896]=C

  const int tid  = threadIdx.x;
  const int wid  = tid >> 6;   // wave id = this wave's d-offset
  const int lane = tid & 63;
  const int hb = blockIdx.x, db = blockIdx.y, n = blockIdx.z;
  const int h0 = hb * 8, d0 = db * 4;
  const int s  = tid & 7;
  const int ht = (tid >> 3) & 7;
  const bool alive = (d0 + wid) < DOUT;  // wave-uniform (only db=7 has dead waves)

  const float* xn = x + (size_t)n * (32u * CH_STRIDE);

  // per-lane staging source offsets (channel-invariant), chunk k = 64*i + lane
  int soff[8];
#pragma unroll
  for (int i = 0; i < 8; ++i) {
    int k   = 64 * i + lane;
    int sd  = k / 160;          // 0..2 real, 3 = pad region (k >= 480)
    int rem = k - sd * 160;
    int rr  = rem >> 4;         // row 0..9
    int p   = rem & 15;         // stored position
    int t1  = (11 * p) & 15;    // pi^{-1}
    int csrc = (t1 < 8) ? (2 * t1) : (2 * ((11 * (p - 8)) & 15) + 1);
    int dd = min(d0 + wid + sd, XD - 1);  // clamp affects only pad/garbage rows
    int hh = min(h0 + rr, XH - 1);
    soff[i] = dd * (XH * XW) + hh * XW + csrc * 4;
  }

  auto stage = [&](float* buf, int ch) {  // 8 always-issued 1KiB DMA loads
    const float* xnc = xn + (size_t)ch * CH_STRIDE;
#pragma unroll
    for (int i = 0; i < 8; ++i) {
      __builtin_amdgcn_global_load_lds(
          (const __attribute__((address_space(1))) void*)(xnc + soff[i]),
          (__attribute__((address_space(3))) void*)(buf + i * 256),  // uniform base
          16, 0, 0);
    }
  };

  // prologue: issue ch0 staging; weight pre-sum overlaps the load latency
  if (alive) stage(&wavebuf[wid][0][0], 0);
  for (int e = tid; e < 864; e += 256) {
    int i = e / 27;
    int j = e - i * 27;
    float ssum = 0.f;
#pragma unroll 8
    for (int o = 0; o < 64; ++o) ssum += cw[o * 864 + e];
    wl[i * 28 + j] = 0.5f * ssum;
  }
  if (tid == 0) {
    float ssum = 0.f;
    for (int o = 0; o < 64; ++o) ssum += 0.5f * cb[o] + pb[o];
    wl[896] = ssum;
  }
  __syncthreads();   // one-time: wl visible (implicit vmcnt(0) drains ch0 loads)
  if (!alive) return;

  const int P0 = (3 * s) & 15;
  const int P1 = (3 * s + 8) & 15;

  float acc[8];
#pragma unroll
  for (int j = 0; j < 8; ++j) acc[j] = 0.f;

#pragma unroll 1
  for (int ch = 0; ch < 32; ++ch) {
    // stage next channel first (dup-stage 31 on last iter keeps vmcnt exact)
    const int chn = (ch < 31) ? ch + 1 : 31;
    stage(&wavebuf[wid][(ch + 1) & 1][0], chn);
    // outstanding = 8 (ch, maybe landed) + 8 (ch+1); wait to <=8 == ch landed
    asm volatile("s_waitcnt vmcnt(8)" ::: "memory");
    __builtin_amdgcn_sched_barrier(0);

    const float* buf = &wavebuf[wid][ch & 1][0];
    float wr[28];
#pragma unroll
    for (int q = 0; q < 7; ++q)
      *(float4*)&wr[4 * q] = *(const float4*)&wl[ch * 28 + 4 * q];

#pragma unroll
    for (int kd = 0; kd < 3; ++kd) {
#pragma unroll
      for (int kh = 0; kh < 3; ++kh) {
        const int base = (kd * 10 + ht + kh) * 64;
        float4 a = *(const float4*)&buf[base + (P0 << 2)];
        float4 b = *(const float4*)&buf[base + (P1 << 2)];
        // xv[8], xv[9] = neighbor strip's a.x, a.y via DPP (no LDS read)
        float x8 = nextlane(a.x);
        float x9 = nextlane(a.y);
        float xv[10] = {a.x, a.y, a.z, a.w, b.x, b.y, b.z, b.w, x8, x9};
        const int wb = kd * 9 + kh * 3;
#pragma unroll
        for (int j = 0; j < 8; ++j)
          acc[j] = fmaf(xv[j], wr[wb],
                   fmaf(xv[j + 1], wr[wb + 1],
                   fmaf(xv[j + 2], wr[wb + 2], acc[j])));
      }
    }

    // WAR: this wave's ds_reads of buf complete before next iter re-stages it
    asm volatile("s_waitcnt lgkmcnt(0)" ::: "memory");
    __builtin_amdgcn_sched_barrier(0);
  }

  // epilogue: out[n][d0+wid][h0+ht][8s..8s+7], masked at ragged edges
  const float Cc  = wl[896];
  const int   dow = d0 + wid, how = h0 + ht;
  if (how < HOUT) {
    float* op = out + (((size_t)n * DOUT + dow) * HOUT + how) * WOUT + s * 8;
    const int nw = min(8, WOUT - s * 8);
#pragma unroll
    for (int j = 0; j < 4; ++j) {
      if (2 * j < nw) {
        float2 v;
        v.x = acc[2 * j] + Cc;
        v.y = acc[2 * j + 1] + Cc;
        *(float2*)&op[2 * j] = v;
      }
    }
  }
}

extern "C" void kernel_launch(void* const* d_in, const int* in_sizes, int n_in,
                              void* d_out, int out_size, void* d_ws, size_t ws_size,
                              hipStream_t stream) {
  const float* x  = (const float*)d_in[0];  // (8,32,32,64,64)
  const float* cw = (const float*)d_in[1];  // (64,32,3,3,3)
  const float* cb = (const float*)d_in[2];  // (64,)
  const float* pb = (const float*)d_in[3];  // (64,1,1,1)
  float* out = (float*)d_out;               // (8,30,62,62)

  dim3 grid(8, 8, 8);  // (hb, db, n) -> 512 blocks = 2 per CU
  conv3d_chansum_kernel<<<grid, 256, 0, stream>>>(x, cw, cb, pb, out);
}